// Round 8
// baseline (1039.778 us; speedup 1.0000x reference)
//
#include <hip/hip_runtime.h>
#include <stdint.h>

// 2-layer LSTM, B=64, T=1024, D=512, H=32, fp32 in/out.
// Phase 1: xg0 = x @ Wih0^T + b0  (fp32 tiled GEMM)
// Phase 2: fused 2-layer scan, ONE WAVE per TWO batches (ILP: two independent
//   recurrence chains interleave to hide dependent-op latency). Zero barriers,
//   zero LDS, zero DS shuffles. Dots: v_dot2_f32_f16 with f16 weights (shared
//   regs across both batches). Cross-lane: permlane32_swap + DPP quad_perm.
//   h broadcast: v_readlane -> wave-uniform SGPRs.

#define TT 1024
#define BB 64
#define DD 512
#define HH 32
#define GG 128  // 4*H
#define RR 2    // batches per wave

typedef _Float16 h2v __attribute__((ext_vector_type(2)));
typedef __fp16 pk2 __attribute__((ext_vector_type(2)));
typedef int int2v __attribute__((ext_vector_type(2)));

__device__ __forceinline__ uint32_t pack2(float lo, float hi) {
  pk2 p = __builtin_amdgcn_cvt_pkrtz(lo, hi);
  return __builtin_bit_cast(uint32_t, p);
}
__device__ __forceinline__ float dot2(uint32_t a, uint32_t b, float acc) {
  return __builtin_amdgcn_fdot2(__builtin_bit_cast(h2v, a),
                                __builtin_bit_cast(h2v, b), acc, false);
}
__device__ __forceinline__ float fast_rcp(float x) { return __builtin_amdgcn_rcpf(x); }
__device__ __forceinline__ float sigm(float s) { return fast_rcp(1.f + __expf(-s)); }
__device__ __forceinline__ float fast_tanh(float x) {
  return fmaf(2.f, fast_rcp(1.f + __expf(-2.f * x)), -1.f);
}
__device__ __forceinline__ float act_sel(float s, bool ist) {
  float z = ist ? s + s : s;
  float r = fast_rcp(1.f + __expf(-z));
  return ist ? fmaf(2.f, r, -1.f) : r;
}

// xor-32 partner, pure VALU; order-proof XOR extraction (verified R6).
__device__ __forceinline__ float partner32(float x) {
  int xi = __builtin_bit_cast(int, x);
#if __has_builtin(__builtin_amdgcn_permlane32_swap)
  int2v r = __builtin_amdgcn_permlane32_swap(xi, xi, false, false);
  return __builtin_bit_cast(float, r.x ^ r.y ^ xi);
#else
  int a = xi, b = xi;
  asm("v_permlane32_swap_b32 %0, %1" : "+v"(a), "+v"(b));
  return __builtin_bit_cast(float, a ^ b ^ xi);
#endif
}

// xor-1 neighbor exchange via DPP quad_perm [1,0,3,2]
__device__ __forceinline__ float xor1_dpp(float x) {
  int xi = __builtin_bit_cast(int, x);
  int r = __builtin_amdgcn_update_dpp(xi, xi, 0xB1, 0xF, 0xF, true);
  return __builtin_bit_cast(float, r);
}

// ---------------- Phase 1: xg GEMM (unchanged, proven) ----------------
__global__ __launch_bounds__(256) void xg_gemm(const float* __restrict__ x,
                                               const float* __restrict__ W,
                                               const float* __restrict__ bih,
                                               const float* __restrict__ bhh,
                                               float* __restrict__ outp) {
  __shared__ float xs[16][68];
  __shared__ float ws[16][128];
  const int tid = threadIdx.x;
  const int m0 = blockIdx.x * 64;
  const int tr = tid >> 5;
  const int tc = tid & 31;
  const int tm = tr * 8;
  const int tn = tc * 4;
  const int sxm = tid >> 2;
  const int sxk = (tid & 3) * 4;
  const int swg = tid >> 1;
  const int swk = (tid & 1) * 8;

  float acc[8][4];
#pragma unroll
  for (int i = 0; i < 8; ++i)
#pragma unroll
    for (int j = 0; j < 4; ++j) acc[i][j] = 0.f;

  for (int k0 = 0; k0 < DD; k0 += 16) {
    const float4 xv = *(const float4*)(x + (size_t)(m0 + sxm) * DD + k0 + sxk);
    xs[sxk + 0][sxm] = xv.x;
    xs[sxk + 1][sxm] = xv.y;
    xs[sxk + 2][sxm] = xv.z;
    xs[sxk + 3][sxm] = xv.w;
    const float4 wv0 = *(const float4*)(W + (size_t)swg * DD + k0 + swk);
    const float4 wv1 = *(const float4*)(W + (size_t)swg * DD + k0 + swk + 4);
    ws[swk + 0][swg] = wv0.x;
    ws[swk + 1][swg] = wv0.y;
    ws[swk + 2][swg] = wv0.z;
    ws[swk + 3][swg] = wv0.w;
    ws[swk + 4][swg] = wv1.x;
    ws[swk + 5][swg] = wv1.y;
    ws[swk + 6][swg] = wv1.z;
    ws[swk + 7][swg] = wv1.w;
    __syncthreads();
#pragma unroll
    for (int k = 0; k < 16; ++k) {
      const float4 a0 = *(const float4*)&xs[k][tm];
      const float4 a1 = *(const float4*)&xs[k][tm + 4];
      const float4 wv = *(const float4*)&ws[k][tn];
      const float xr[8] = {a0.x, a0.y, a0.z, a0.w, a1.x, a1.y, a1.z, a1.w};
      const float wr[4] = {wv.x, wv.y, wv.z, wv.w};
#pragma unroll
      for (int i = 0; i < 8; ++i)
#pragma unroll
        for (int j = 0; j < 4; ++j) acc[i][j] = fmaf(xr[i], wr[j], acc[i][j]);
    }
    __syncthreads();
  }
  const float4 bi = *(const float4*)(bih + tn);
  const float4 bh = *(const float4*)(bhh + tn);
  const float bs[4] = {bi.x + bh.x, bi.y + bh.y, bi.z + bh.z, bi.w + bh.w};
#pragma unroll
  for (int i = 0; i < 8; ++i) {
    float4 o;
    o.x = acc[i][0] + bs[0];
    o.y = acc[i][1] + bs[1];
    o.z = acc[i][2] + bs[2];
    o.w = acc[i][3] + bs[3];
    *(float4*)(outp + (size_t)(m0 + tm + i) * GG + tn) = o;
  }
}

// ---------------- Phase 2: 2-batches-per-wave scan ----------------
// Lane l: j = l&31, hi = l>>5. gA = j+64*hi (i/g gate), gB = gA+32 (f/o gate).
// Weights shared across the RR batches; per-batch state duplicated.
__global__ __launch_bounds__(64, 1) void lstm_scan(const float* __restrict__ xg,
                                                   const float* __restrict__ Whh0,
                                                   const float* __restrict__ Wih1,
                                                   const float* __restrict__ Whh1,
                                                   const float* __restrict__ bih1,
                                                   const float* __restrict__ bhh1,
                                                   float* __restrict__ out) {
  const int l = threadIdx.x;
  const int j = l & 31;
  const int hi = l >> 5;
  const int b0 = blockIdx.x * RR;
  const int gA = j + 64 * hi;
  const int gB = gA + 32;

  uint32_t w0A[16], w0B[16], wiA[16], whA[16], wiB[16], whB[16];
#pragma unroll
  for (int q = 0; q < 8; ++q) {
    float4 a = *(const float4*)(Whh0 + (size_t)gA * HH + q * 4);
    float4 c = *(const float4*)(Whh0 + (size_t)gB * HH + q * 4);
    w0A[2 * q] = pack2(a.x, a.y); w0A[2 * q + 1] = pack2(a.z, a.w);
    w0B[2 * q] = pack2(c.x, c.y); w0B[2 * q + 1] = pack2(c.z, c.w);
    float4 d = *(const float4*)(Wih1 + (size_t)gA * HH + q * 4);
    float4 e = *(const float4*)(Wih1 + (size_t)gB * HH + q * 4);
    wiA[2 * q] = pack2(d.x, d.y); wiA[2 * q + 1] = pack2(d.z, d.w);
    wiB[2 * q] = pack2(e.x, e.y); wiB[2 * q + 1] = pack2(e.z, e.w);
    float4 f = *(const float4*)(Whh1 + (size_t)gA * HH + q * 4);
    float4 g = *(const float4*)(Whh1 + (size_t)gB * HH + q * 4);
    whA[2 * q] = pack2(f.x, f.y); whA[2 * q + 1] = pack2(f.z, f.w);
    whB[2 * q] = pack2(g.x, g.y); whB[2 * q + 1] = pack2(g.z, g.w);
  }
  const float b1A = bih1[gA] + bhh1[gA];
  const float b1B = bih1[gB] + bhh1[gB];

  uint32_t h0p[RR][16], h1p[RR][16];
  float c0[RR], c1[RR];
#pragma unroll
  for (int r = 0; r < RR; ++r) {
    c0[r] = 0.f; c1[r] = 0.f;
#pragma unroll
    for (int k = 0; k < 16; ++k) { h0p[r][k] = 0u; h1p[r][k] = 0u; }
  }

  const float* xgp[RR];
  float* outp[RR];
#pragma unroll
  for (int r = 0; r < RR; ++r) {
    xgp[r] = xg + (size_t)(b0 + r) * TT * GG;
    outp[r] = out + (size_t)(b0 + r) * TT * HH;
  }

  // xg prefetch ring, depth 4
  float xA[RR][4], xB[RR][4];
#pragma unroll
  for (int r = 0; r < RR; ++r)
#pragma unroll
    for (int u = 0; u < 4; ++u) {
      xA[r][u] = xgp[r][u * GG + gA];
      xB[r][u] = xgp[r][u * GG + gB];
    }

  for (int tb = 0; tb < TT; tb += 4) {
#pragma unroll
    for (int u = 0; u < 4; ++u) {
      const int t = tb + u;
      const int tp = (t + 4 < TT) ? (t + 4) : (TT - 1);
      float sA0[RR], sB0[RR], sA1[RR], sB1[RR];
      // ---- dots for both batches (independent chains -> ILP) ----
#pragma unroll
      for (int r = 0; r < RR; ++r) {
        float s0 = xA[r][u], s1 = xB[r][u];
        xA[r][u] = xgp[r][(size_t)tp * GG + gA];
        xB[r][u] = xgp[r][(size_t)tp * GG + gB];
        float pA = 0.f, pB = 0.f;
#pragma unroll
        for (int k = 0; k < 16; k += 2) {
          s0 = dot2(w0A[k], h0p[r][k], s0);
          pA = dot2(w0A[k + 1], h0p[r][k + 1], pA);
          s1 = dot2(w0B[k], h0p[r][k], s1);
          pB = dot2(w0B[k + 1], h0p[r][k + 1], pB);
        }
        sA0[r] = s0 + pA; sB0[r] = s1 + pB;
        float a1 = b1A, b1 = b1B, qA = 0.f, qB = 0.f;
#pragma unroll
        for (int k = 0; k < 16; k += 2) {
          a1 = dot2(wiA[k], h0p[r][k], a1);
          qA = dot2(wiA[k + 1], h0p[r][k + 1], qA);
          b1 = dot2(wiB[k], h0p[r][k], b1);
          qB = dot2(wiB[k + 1], h0p[r][k + 1], qB);
          a1 = dot2(whA[k], h1p[r][k], a1);
          qA = dot2(whA[k + 1], h1p[r][k + 1], qA);
          b1 = dot2(whB[k], h1p[r][k], b1);
          qB = dot2(whB[k + 1], h1p[r][k + 1], qB);
        }
        sA1[r] = a1 + qA; sB1[r] = b1 + qB;
      }
      // ---- layer0 combine -> h0[t] (both batches interleaved) ----
#pragma unroll
      for (int r = 0; r < RR; ++r) {
        float aA = act_sel(sA0[r], hi != 0);  // i (hi=0) / g (hi=1)
        float aB = sigm(sB0[r]);              // f (hi=0) / o (hi=1)
        float pAx = partner32(aA);
        float pBx = partner32(aB);
        float gi = hi ? pAx : aA;
        float gf = hi ? pBx : aB;
        float gg = hi ? aA : pAx;
        float go = hi ? aB : pBx;
        c0[r] = fmaf(gf, c0[r], gi * gg);
        float h = go * fast_tanh(c0[r]);
        float oth = xor1_dpp(h);
        float lo = (j & 1) ? oth : h;
        float hh = (j & 1) ? h : oth;
        uint32_t pk = pack2(lo, hh);
#pragma unroll
        for (int m = 0; m < 16; ++m)
          h0p[r][m] = (uint32_t)__builtin_amdgcn_readlane((int)pk, 2 * m);
      }
      // ---- layer1 combine for step t-1 ----
      if (t > 0) {
#pragma unroll
        for (int r = 0; r < RR; ++r) {
          float aA = act_sel(sA1[r], hi != 0);
          float aB = sigm(sB1[r]);
          float pAx = partner32(aA);
          float pBx = partner32(aB);
          float gi = hi ? pAx : aA;
          float gf = hi ? pBx : aB;
          float gg = hi ? aA : pAx;
          float go = hi ? aB : pBx;
          c1[r] = fmaf(gf, c1[r], gi * gg);
          float h = go * fast_tanh(c1[r]);
          if (!hi) outp[r][(size_t)(t - 1) * HH + j] = h;
          float oth = xor1_dpp(h);
          float lo = (j & 1) ? oth : h;
          float hh = (j & 1) ? h : oth;
          uint32_t pk = pack2(lo, hh);
#pragma unroll
          for (int m = 0; m < 16; ++m)
            h1p[r][m] = (uint32_t)__builtin_amdgcn_readlane((int)pk, 2 * m);
        }
      }
    }
  }
  // ---- final layer1 step (t = TT-1) ----
#pragma unroll
  for (int r = 0; r < RR; ++r) {
    float a1 = b1A, b1 = b1B, qA = 0.f, qB = 0.f;
#pragma unroll
    for (int k = 0; k < 16; k += 2) {
      a1 = dot2(wiA[k], h0p[r][k], a1);
      qA = dot2(wiA[k + 1], h0p[r][k + 1], qA);
      b1 = dot2(wiB[k], h0p[r][k], b1);
      qB = dot2(wiB[k + 1], h0p[r][k + 1], qB);
      a1 = dot2(whA[k], h1p[r][k], a1);
      qA = dot2(whA[k + 1], h1p[r][k + 1], qA);
      b1 = dot2(whB[k], h1p[r][k], b1);
      qB = dot2(whB[k + 1], h1p[r][k + 1], qB);
    }
    float sA1 = a1 + qA, sB1 = b1 + qB;
    float aA = act_sel(sA1, hi != 0);
    float aB = sigm(sB1);
    float pAx = partner32(aA);
    float pBx = partner32(aB);
    float gi = hi ? pAx : aA;
    float gf = hi ? pBx : aB;
    float gg = hi ? aA : pAx;
    float go = hi ? aB : pBx;
    c1[r] = fmaf(gf, c1[r], gi * gg);
    float h = go * fast_tanh(c1[r]);
    if (!hi) outp[r][(size_t)(TT - 1) * HH + j] = h;
  }
}

extern "C" void kernel_launch(void* const* d_in, const int* in_sizes, int n_in,
                              void* d_out, int out_size, void* d_ws, size_t ws_size,
                              hipStream_t stream) {
  const float* x = (const float*)d_in[0];
  const float* Wih0 = (const float*)d_in[1];
  const float* Whh0 = (const float*)d_in[2];
  const float* bih0 = (const float*)d_in[3];
  const float* bhh0 = (const float*)d_in[4];
  const float* Wih1 = (const float*)d_in[5];
  const float* Whh1 = (const float*)d_in[6];
  const float* bih1 = (const float*)d_in[7];
  const float* bhh1 = (const float*)d_in[8];
  float* out = (float*)d_out;
  float* xg = (float*)d_ws;  // B*T*4H*4 = 33.5 MB scratch

  xg_gemm<<<dim3((BB * TT) / 64), dim3(256), 0, stream>>>(x, Wih0, bih0, bhh0, xg);
  lstm_scan<<<dim3(BB / RR), dim3(64), 0, stream>>>(xg, Whh0, Wih1, Whh1, bih1, bhh1, out);
}

// Round 9
// 715.077 us; speedup vs baseline: 1.4541x; 1.4541x over previous
//
#include <hip/hip_runtime.h>
#include <stdint.h>

// 2-layer LSTM, B=64, T=1024, D=512, H=32, fp32 in/out.
// Phase 1: xg0 = x @ Wih0^T + b0  (fp32 tiled GEMM)
// Phase 2: scan0 = layer-0 recurrence only (1 wave/batch, issue-bound ~95 instr/step),
//          writes h0[t] as 16 dwords of packed f16 into out[b][t][0..15] (scratch).
// Phase 3: scan1 = layer-1 recurrence, reads h0[t] via wave-uniform loads
//          (double-buffered), overwrites out[b][t][:] with h1[t] (f32).
// Rationale: single-wave scan measured ~84% VALU-issue-bound (R6/R8); splitting
// layers across two kernels halves instructions per wave-step.

#define TT 1024
#define BB 64
#define DD 512
#define HH 32
#define GG 128  // 4*H

typedef _Float16 h2v __attribute__((ext_vector_type(2)));
typedef __fp16 pk2 __attribute__((ext_vector_type(2)));
typedef int int2v __attribute__((ext_vector_type(2)));

__device__ __forceinline__ uint32_t pack2(float lo, float hi) {
  pk2 p = __builtin_amdgcn_cvt_pkrtz(lo, hi);
  return __builtin_bit_cast(uint32_t, p);
}
__device__ __forceinline__ float dot2(uint32_t a, uint32_t b, float acc) {
  return __builtin_amdgcn_fdot2(__builtin_bit_cast(h2v, a),
                                __builtin_bit_cast(h2v, b), acc, false);
}
__device__ __forceinline__ float fast_rcp(float x) { return __builtin_amdgcn_rcpf(x); }
__device__ __forceinline__ float sigm(float s) { return fast_rcp(1.f + __expf(-s)); }
__device__ __forceinline__ float fast_tanh(float x) {
  return fmaf(2.f, fast_rcp(1.f + __expf(-2.f * x)), -1.f);
}
__device__ __forceinline__ float act_sel(float s, bool ist) {
  float z = ist ? s + s : s;
  float r = fast_rcp(1.f + __expf(-z));
  return ist ? fmaf(2.f, r, -1.f) : r;
}

// xor-32 partner, pure VALU; order-proof XOR extraction (verified R6).
__device__ __forceinline__ float partner32(float x) {
  int xi = __builtin_bit_cast(int, x);
#if __has_builtin(__builtin_amdgcn_permlane32_swap)
  int2v r = __builtin_amdgcn_permlane32_swap(xi, xi, false, false);
  return __builtin_bit_cast(float, r.x ^ r.y ^ xi);
#else
  int a = xi, b = xi;
  asm("v_permlane32_swap_b32 %0, %1" : "+v"(a), "+v"(b));
  return __builtin_bit_cast(float, a ^ b ^ xi);
#endif
}

// xor-1 neighbor exchange via DPP quad_perm [1,0,3,2]
__device__ __forceinline__ float xor1_dpp(float x) {
  int xi = __builtin_bit_cast(int, x);
  int r = __builtin_amdgcn_update_dpp(xi, xi, 0xB1, 0xF, 0xF, true);
  return __builtin_bit_cast(float, r);
}

// ---------------- Phase 1: xg GEMM (unchanged, proven) ----------------
__global__ __launch_bounds__(256) void xg_gemm(const float* __restrict__ x,
                                               const float* __restrict__ W,
                                               const float* __restrict__ bih,
                                               const float* __restrict__ bhh,
                                               float* __restrict__ outp) {
  __shared__ float xs[16][68];
  __shared__ float ws[16][128];
  const int tid = threadIdx.x;
  const int m0 = blockIdx.x * 64;
  const int tr = tid >> 5;
  const int tc = tid & 31;
  const int tm = tr * 8;
  const int tn = tc * 4;
  const int sxm = tid >> 2;
  const int sxk = (tid & 3) * 4;
  const int swg = tid >> 1;
  const int swk = (tid & 1) * 8;

  float acc[8][4];
#pragma unroll
  for (int i = 0; i < 8; ++i)
#pragma unroll
    for (int j = 0; j < 4; ++j) acc[i][j] = 0.f;

  for (int k0 = 0; k0 < DD; k0 += 16) {
    const float4 xv = *(const float4*)(x + (size_t)(m0 + sxm) * DD + k0 + sxk);
    xs[sxk + 0][sxm] = xv.x;
    xs[sxk + 1][sxm] = xv.y;
    xs[sxk + 2][sxm] = xv.z;
    xs[sxk + 3][sxm] = xv.w;
    const float4 wv0 = *(const float4*)(W + (size_t)swg * DD + k0 + swk);
    const float4 wv1 = *(const float4*)(W + (size_t)swg * DD + k0 + swk + 4);
    ws[swk + 0][swg] = wv0.x;
    ws[swk + 1][swg] = wv0.y;
    ws[swk + 2][swg] = wv0.z;
    ws[swk + 3][swg] = wv0.w;
    ws[swk + 4][swg] = wv1.x;
    ws[swk + 5][swg] = wv1.y;
    ws[swk + 6][swg] = wv1.z;
    ws[swk + 7][swg] = wv1.w;
    __syncthreads();
#pragma unroll
    for (int k = 0; k < 16; ++k) {
      const float4 a0 = *(const float4*)&xs[k][tm];
      const float4 a1 = *(const float4*)&xs[k][tm + 4];
      const float4 wv = *(const float4*)&ws[k][tn];
      const float xr[8] = {a0.x, a0.y, a0.z, a0.w, a1.x, a1.y, a1.z, a1.w};
      const float wr[4] = {wv.x, wv.y, wv.z, wv.w};
#pragma unroll
      for (int i = 0; i < 8; ++i)
#pragma unroll
        for (int j = 0; j < 4; ++j) acc[i][j] = fmaf(xr[i], wr[j], acc[i][j]);
    }
    __syncthreads();
  }
  const float4 bi = *(const float4*)(bih + tn);
  const float4 bh = *(const float4*)(bhh + tn);
  const float bs[4] = {bi.x + bh.x, bi.y + bh.y, bi.z + bh.z, bi.w + bh.w};
#pragma unroll
  for (int i = 0; i < 8; ++i) {
    float4 o;
    o.x = acc[i][0] + bs[0];
    o.y = acc[i][1] + bs[1];
    o.z = acc[i][2] + bs[2];
    o.w = acc[i][3] + bs[3];
    *(float4*)(outp + (size_t)(m0 + tm + i) * GG + tn) = o;
  }
}

// ---------------- Phase 2: layer-0 scan ----------------
// 64 blocks x 64 threads. Lane l: j=l&31, hi=l>>5; gA=j+64*hi, gB=gA+32.
// h0[t] written as 16 dwords (packed f16 pairs) into out[b][t][0..15].
__global__ __launch_bounds__(64, 1) void lstm_scan0(const float* __restrict__ xg,
                                                    const float* __restrict__ Whh0,
                                                    uint32_t* h0out) {
  const int l = threadIdx.x;
  const int j = l & 31;
  const int hi = l >> 5;
  const int b = blockIdx.x;
  const int gA = j + 64 * hi;
  const int gB = gA + 32;

  uint32_t w0A[16], w0B[16];
#pragma unroll
  for (int q = 0; q < 8; ++q) {
    float4 a = *(const float4*)(Whh0 + (size_t)gA * HH + q * 4);
    float4 c = *(const float4*)(Whh0 + (size_t)gB * HH + q * 4);
    w0A[2 * q] = pack2(a.x, a.y); w0A[2 * q + 1] = pack2(a.z, a.w);
    w0B[2 * q] = pack2(c.x, c.y); w0B[2 * q + 1] = pack2(c.z, c.w);
  }

  uint32_t h0p[16];
#pragma unroll
  for (int k = 0; k < 16; ++k) h0p[k] = 0u;
  float c0 = 0.f;

  const float* xgp = xg + (size_t)b * TT * GG;
  uint32_t* hop = h0out + (size_t)b * TT * 32;  // 32-dword slots (out[b][t][:])

  float xA[4], xB[4];
#pragma unroll
  for (int u = 0; u < 4; ++u) {
    xA[u] = xgp[u * GG + gA];
    xB[u] = xgp[u * GG + gB];
  }

  const bool is_writer = (!hi) && ((j & 1) == 0);  // 16 lanes, even j, lo half

  for (int tb = 0; tb < TT; tb += 4) {
#pragma unroll
    for (int u = 0; u < 4; ++u) {
      const int t = tb + u;
      float sA0 = xA[u], sB0 = xB[u];
      const int tp = (t + 4 < TT) ? (t + 4) : (TT - 1);
      xA[u] = xgp[(size_t)tp * GG + gA];
      xB[u] = xgp[(size_t)tp * GG + gB];
      float pA = 0.f, pB = 0.f;
#pragma unroll
      for (int k = 0; k < 16; k += 2) {
        sA0 = dot2(w0A[k], h0p[k], sA0);
        pA  = dot2(w0A[k + 1], h0p[k + 1], pA);
        sB0 = dot2(w0B[k], h0p[k], sB0);
        pB  = dot2(w0B[k + 1], h0p[k + 1], pB);
      }
      sA0 += pA; sB0 += pB;
      float aA = act_sel(sA0, hi != 0);  // i (hi=0) / g (hi=1)
      float aB = sigm(sB0);              // f (hi=0) / o (hi=1)
      float pAx = partner32(aA);
      float pBx = partner32(aB);
      float gi = hi ? pAx : aA;
      float gf = hi ? pBx : aB;
      float gg = hi ? aA : pAx;
      float go = hi ? aB : pBx;
      c0 = fmaf(gf, c0, gi * gg);
      float h = go * fast_tanh(c0);
      float oth = xor1_dpp(h);
      float lo = (j & 1) ? oth : h;
      float hh = (j & 1) ? h : oth;
      uint32_t pk = pack2(lo, hh);  // lane j (even): {h[j], h[j+1]}
      if (is_writer) hop[(size_t)t * 32 + (j >> 1)] = pk;
#pragma unroll
      for (int m = 0; m < 16; ++m)
        h0p[m] = (uint32_t)__builtin_amdgcn_readlane((int)pk, 2 * m);
    }
  }
}

// ---------------- Phase 3: layer-1 scan ----------------
// Reads h0[t] (16 dwords, wave-uniform) from out[b][t][0..15], computes h1[t],
// overwrites out[b][t][0..31] with f32 h1 (read-before-write within the step).
__global__ __launch_bounds__(64, 1) void lstm_scan1(const float* __restrict__ Wih1,
                                                    const float* __restrict__ Whh1,
                                                    const float* __restrict__ bih1,
                                                    const float* __restrict__ bhh1,
                                                    float* out) {
  const int l = threadIdx.x;
  const int j = l & 31;
  const int hi = l >> 5;
  const int b = blockIdx.x;
  const int gA = j + 64 * hi;
  const int gB = gA + 32;

  uint32_t wiA[16], whA[16], wiB[16], whB[16];
#pragma unroll
  for (int q = 0; q < 8; ++q) {
    float4 d = *(const float4*)(Wih1 + (size_t)gA * HH + q * 4);
    float4 e = *(const float4*)(Wih1 + (size_t)gB * HH + q * 4);
    wiA[2 * q] = pack2(d.x, d.y); wiA[2 * q + 1] = pack2(d.z, d.w);
    wiB[2 * q] = pack2(e.x, e.y); wiB[2 * q + 1] = pack2(e.z, e.w);
    float4 f = *(const float4*)(Whh1 + (size_t)gA * HH + q * 4);
    float4 g = *(const float4*)(Whh1 + (size_t)gB * HH + q * 4);
    whA[2 * q] = pack2(f.x, f.y); whA[2 * q + 1] = pack2(f.z, f.w);
    whB[2 * q] = pack2(g.x, g.y); whB[2 * q + 1] = pack2(g.z, g.w);
  }
  const float b1A = bih1[gA] + bhh1[gA];
  const float b1B = bih1[gB] + bhh1[gB];

  uint32_t h1p[16];
#pragma unroll
  for (int k = 0; k < 16; ++k) h1p[k] = 0u;
  float c1 = 0.f;

  const uint32_t* h0in = (const uint32_t*)out + (size_t)b * TT * 32;
  float* outp = out + (size_t)b * TT * 32;

  uint32_t h0a[16], h0b[16];
#pragma unroll
  for (int m = 0; m < 16; ++m) h0a[m] = h0in[m];  // h0[0]

  auto STEP = [&](int t, uint32_t* cur, uint32_t* nxt) {
    // prefetch h0[t+1] (clamped; redundant at tail, harmless)
    const int tp = (t + 1 < TT) ? (t + 1) : (TT - 1);
#pragma unroll
    for (int m = 0; m < 16; ++m) nxt[m] = h0in[(size_t)tp * 32 + m];
    // dots: Whh1*h1 first (independent of prefetch), then Wih1*h0(cur)
    float a1 = b1A, bq = b1B, qA = 0.f, qB = 0.f;
#pragma unroll
    for (int k = 0; k < 16; k += 2) {
      a1 = dot2(whA[k], h1p[k], a1);
      qA = dot2(whA[k + 1], h1p[k + 1], qA);
      bq = dot2(whB[k], h1p[k], bq);
      qB = dot2(whB[k + 1], h1p[k + 1], qB);
    }
#pragma unroll
    for (int k = 0; k < 16; k += 2) {
      a1 = dot2(wiA[k], cur[k], a1);
      qA = dot2(wiA[k + 1], cur[k + 1], qA);
      bq = dot2(wiB[k], cur[k], bq);
      qB = dot2(wiB[k + 1], cur[k + 1], qB);
    }
    float sA1 = a1 + qA, sB1 = bq + qB;
    float aA = act_sel(sA1, hi != 0);
    float aB = sigm(sB1);
    float pAx = partner32(aA);
    float pBx = partner32(aB);
    float gi = hi ? pAx : aA;
    float gf = hi ? pBx : aB;
    float gg = hi ? aA : pAx;
    float go = hi ? aB : pBx;
    c1 = fmaf(gf, c1, gi * gg);
    float h = go * fast_tanh(c1);
    if (!hi) outp[(size_t)t * 32 + j] = h;  // overwrite slot t (h0[t] already consumed)
    float oth = xor1_dpp(h);
    float lo = (j & 1) ? oth : h;
    float hh = (j & 1) ? h : oth;
    uint32_t pk = pack2(lo, hh);
#pragma unroll
    for (int m = 0; m < 16; ++m)
      h1p[m] = (uint32_t)__builtin_amdgcn_readlane((int)pk, 2 * m);
  };

  for (int t = 0; t < TT; t += 2) {
    STEP(t, h0a, h0b);
    STEP(t + 1, h0b, h0a);
  }
}

extern "C" void kernel_launch(void* const* d_in, const int* in_sizes, int n_in,
                              void* d_out, int out_size, void* d_ws, size_t ws_size,
                              hipStream_t stream) {
  const float* x = (const float*)d_in[0];
  const float* Wih0 = (const float*)d_in[1];
  const float* Whh0 = (const float*)d_in[2];
  const float* bih0 = (const float*)d_in[3];
  const float* bhh0 = (const float*)d_in[4];
  const float* Wih1 = (const float*)d_in[5];
  const float* Whh1 = (const float*)d_in[6];
  const float* bih1 = (const float*)d_in[7];
  const float* bhh1 = (const float*)d_in[8];
  float* out = (float*)d_out;
  float* xg = (float*)d_ws;  // B*T*4H*4 = 33.5 MB scratch

  xg_gemm<<<dim3((BB * TT) / 64), dim3(256), 0, stream>>>(x, Wih0, bih0, bhh0, xg);
  lstm_scan0<<<dim3(BB), dim3(64), 0, stream>>>(xg, Whh0, (uint32_t*)out);
  lstm_scan1<<<dim3(BB), dim3(64), 0, stream>>>(Wih1, Whh1, bih1, bhh1, out);
}